// Round 1
// baseline (1009.350 us; speedup 1.0000x reference)
//
#include <hip/hip_runtime.h>

#define SL 256
#define BATCH 8
#define NT 1024
#define W0 32
#define LDSF 33152                 // padded packed triangle (floats), 16B-aligned rows
#define REDF 32
#define TABF 256
#define LDSB ((LDSF + REDF + TABF) * 4)   // 133,760 B dynamic LDS

// Row j (j in [1,255], holding cells (k,j), k=0..j-1) packed: rows j and 256-j
// share a 260-float slot; every row base is 16B-aligned.
__device__ __forceinline__ int rowOff(int j) {
  if (j <= 127) return (j - 1) * 260;
  if (j == 128) return 127 * 260;
  int jp = 256 - j;                       // 1..127
  return (jp - 1) * 260 + ((jp + 3) & ~3);
}

template <int G>
__device__ __forceinline__ float grpSum(float v) {
#pragma unroll
  for (int o = G >> 1; o; o >>= 1) v += __shfl_xor(v, o, 64);
  return v;
}

// Raw barrier draining only LDS ops: global stores (g output) float across it.
__device__ __forceinline__ void barrier_lgkm() {
  __builtin_amdgcn_sched_barrier(0);
  asm volatile("s_waitcnt lgkmcnt(0)" ::: "memory");
  __builtin_amdgcn_s_barrier();
  __builtin_amdgcn_sched_barrier(0);
}

// Rescale LDS E triangle by exp(-dc*width) for all computed widths <= wcur.
__device__ void rescaleE(int tid, float dc, int wcur, float* sh) {
  const int lane = tid & 63, wave = tid >> 6;
  for (int j = 1 + wave; j < SL; j += 16) {
    int jlo = j - wcur; if (jlo < 0) jlo = 0;
    int base = rowOff(j);
    for (int i = jlo + lane; i < j; i += 64)
      sh[base + i] *= __expf(-dc * (float)(j - i));
  }
}

// Inside widths [w0,w1]: R = sum_k E[i,k]*E[k,j]; E_cell = R*exp(sc).
// Both operands from LDS: E[k,j] contiguous in row j; E[i,k] gathered via tab.
template <int G>
__device__ __forceinline__ void insideB(int w0, int w1, int tid,
    const float* __restrict__ sc, float* __restrict__ sh,
    float* __restrict__ red, const int* __restrict__ tab) {
  constexpr int LG = (G == 4) ? 2 : (G == 8) ? 3 : (G == 16) ? 4 : (G == 32) ? 5 : 6;
  const int c = tid >> LG, lig = tid & (G - 1);
  for (int w = w0; w <= w1; ++w) {
    // flag written during step w-1 (ping-pong) -> branch latency overlaps compute
    const float fl = red[16 + ((w - 1) & 1)];
    if (c < SL - w) {
      const int i = c, j = i + w;
      const int oj = tab[j];
      float scv = 0.f;
      if (lig == 0) scv = sc[i * SL + j];
      float a0 = 0.f, a1 = 0.f;
      for (int s4 = ((i + 1) & ~3) + 4 * lig; s4 < j; s4 += 4 * G) {
        float4 bv = *(const float4*)(sh + oj + s4);     // E[k,j], contiguous b128
        int4 tv = *(const int4*)(tab + s4);             // rowOff(k) x4, b128
        float e0 = sh[tv.x + i];                        // E[i,k] gather
        float e1 = sh[tv.y + i];
        float e2 = sh[tv.z + i];
        float e3 = sh[tv.w + i];
        // k <= i reads neighbor-row garbage -> mask. k >= j reads zero cells (ok).
        a0 = fmaf((s4 + 0 > i) ? e0 : 0.f, bv.x, a0);
        a1 = fmaf((s4 + 1 > i) ? e1 : 0.f, bv.y, a1);
        a0 = fmaf((s4 + 2 > i) ? e2 : 0.f, bv.z, a0);
        a1 = fmaf((s4 + 3 > i) ? e3 : 0.f, bv.w, a1);
      }
      float acc = grpSum<G>(a0 + a1);
      if (lig == 0) {
        sh[oj + i] = acc * __expf(scv);
        if (acc > 3.5e19f || acc < 3e-16f) red[16 + (w & 1)] = fmaxf(acc, 1e-30f);
      }
    }
    __syncthreads();            // vmcnt already ~0: no global stores in this loop
    if (fl != 0.f) {            // uniform; rescale deferred one step (safe: ~1e15 headroom)
      float dc = (__logf(fl) + 8.0f) / (float)w;
      rescaleE(tid, dc, w, sh);
      __syncthreads();
      if (tid == 0) { red[16] = 0.f; red[17] = 0.f; }  // clear both (step-w dets are stale)
      __syncthreads();
    }
  }
}

// Outside widths w0 down to w1: g = E_pq * (sum_j E[q,j]H[p,j] + sum_i E[i,p]H[i,q]).
// H lives in LDS (gather row / contiguous col); E is read-only from global Eg/ETg.
template <int G>
__device__ __forceinline__ void outsideB(int w0, int w1, int tid,
    const float* __restrict__ sc, float* __restrict__ gOut,
    const float* __restrict__ Eg, const float* __restrict__ ETg,
    float* __restrict__ shH, const int* __restrict__ tab) {
  constexpr int LG = (G == 4) ? 2 : (G == 8) ? 3 : (G == 16) ? 4 : (G == 32) ? 5 : 6;
  const int c = tid >> LG, lig = tid & (G - 1);
  for (int w = w0; w >= w1; --w) {
    if (c < SL - w) {
      const int p = c, q = p + w;
      float scv = 0.f, Epq = 0.f;
      if (lig == 0) { scv = sc[p * SL + q]; Epq = Eg[p * SL + q]; }
      float a0 = 0.f, a1 = 0.f;
      const float* er = Eg + q * SL;                    // E row q, read-only L2
      for (int s4 = ((q + 1) & ~3) + 4 * lig; s4 < SL; s4 += 4 * G) {
        float4 ev = *(const float4*)(er + s4);
        int4 tv = *(const int4*)(tab + s4);
        float h0 = shH[tv.x + p];                       // H[p,j] gather
        float h1 = shH[tv.y + p];
        float h2 = shH[tv.z + p];
        float h3 = shH[tv.w + p];
        a0 = fmaf(ev.x, (s4 + 0 > q) ? h0 : 0.f, a0);
        a1 = fmaf(ev.y, (s4 + 1 > q) ? h1 : 0.f, a1);
        a0 = fmaf(ev.z, (s4 + 2 > q) ? h2 : 0.f, a0);
        a1 = fmaf(ev.w, (s4 + 3 > q) ? h3 : 0.f, a1);
      }
      if (p > 0) {
        const float* et = ETg + p * SL;                 // E column p, read-only L2
        const float* hq = shH + tab[q];                 // H column q, contiguous LDS
        for (int s4 = 4 * lig; s4 < p; s4 += 4 * G) {
          float4 ev = *(const float4*)(et + s4);        // zero for i >= p (memset guard)
          float4 hv = *(const float4*)(hq + s4);
          a0 = fmaf(ev.x, hv.x, a0);
          a1 = fmaf(ev.y, hv.y, a1);
          a0 = fmaf(ev.z, hv.z, a0);
          a1 = fmaf(ev.w, hv.w, a1);
        }
      }
      float acc = grpSum<G>(a0 + a1);
      if (lig == 0) {
        gOut[p * SL + q] = Epq * acc;                   // store floats across raw barrier
        shH[tab[q] + p] = acc * __expf(scv);
      }
    }
    barrier_lgkm();
  }
}

__global__ __launch_bounds__(NT) void cyk_exp(
    const float* __restrict__ scores, float* __restrict__ out,
    float* __restrict__ ws) {
  extern __shared__ float sh[];
  float* red = sh + LDSF;
  int* tab = (int*)(sh + LDSF + REDF);
  const int b = blockIdx.x;
  const int tid = threadIdx.x;
  const int lane = tid & 63;
  const int wave = tid >> 6;
  const size_t P = (size_t)SL * SL;
  const float* sc = scores + (size_t)b * P;
  float* g   = out + (size_t)b * P;
  float* Eg  = ws + (size_t)b * P;                 // E row-major (read-only after dump)
  float* ETg = ws + (size_t)(BATCH + b) * P;       // E col-major (read-only after dump)

  for (int idx = tid * 4; idx < LDSF; idx += NT * 4)
    *(float4*)(sh + idx) = make_float4(0.f, 0.f, 0.f, 0.f);
  if (tid < REDF) red[tid] = 0.f;
  if (tid < 256) tab[tid] = rowOff(tid == 0 ? 1 : tid);
  __syncthreads();

  // width 1: store s = sc (log space for phase A)
  for (int i = tid; i < SL - 1; i += NT)
    sh[tab[i + 1] + i] = sc[i * SL + i + 1];
  __syncthreads();

  // ---- phase A: widths 2..W0, log space ----
  {
    const int c4 = tid >> 2, lig = tid & 3;
    for (int w = 2; w <= W0; ++w) {
      if (c4 < SL - w) {
        const int i = c4, j = i + w;
        const int oj = tab[j];
        float scv = 0.f;
        if (lig == 0) scv = sc[i * SL + j];
        float m = -1e30f, sum = 0.f;
        for (int k = i + 1 + lig; k < j; k += 4) {
          float t = sh[tab[k] + i] + sh[oj + k];
          float nm = fmaxf(m, t);
          sum = sum * __expf(m - nm) + __expf(t - nm);
          m = nm;
        }
#pragma unroll
        for (int o = 2; o; o >>= 1) {
          float mo = __shfl_xor(m, o, 64);
          float so = __shfl_xor(sum, o, 64);
          float nm = fmaxf(m, mo);
          sum = sum * __expf(m - nm) + so * __expf(mo - nm);
          m = nm;
        }
        if (lig == 0) sh[oj + i] = scv + m + __logf(sum);
      }
      __syncthreads();
    }
  }

  // ---- calibrate c = max(s at width W0)/W0 ----
  {
    int idx = tid < SL - W0 ? tid : SL - W0 - 1;
    float v = sh[tab[idx + W0] + idx];
#pragma unroll
    for (int o = 32; o; o >>= 1) v = fmaxf(v, __shfl_xor(v, o, 64));
    if (lane == 0) red[wave] = v;
  }
  __syncthreads();
  float cc;
  {
    float mx = red[0];
#pragma unroll
    for (int t = 1; t < 16; ++t) mx = fmaxf(mx, red[t]);
    cc = mx / (float)W0;
  }

  // ---- convert widths 1..W0 to E-space (LDS only) ----
  for (int w = 1; w <= W0; ++w) {
    for (int i = tid; i < SL - w; i += NT) {
      int o = tab[i + w] + i;
      sh[o] = __expf(sh[o] - cc * (float)w);
    }
  }
  __syncthreads();

  // ---- phase B inside: LDS-only fma dot products ----
  insideB<4>(W0 + 1, 127, tid, sc, sh, red, tab);
  insideB<8>(128, 191, tid, sc, sh, red, tab);
  insideB<16>(192, 223, tid, sc, sh, red, tab);
  insideB<32>(224, 239, tid, sc, sh, red, tab);
  insideB<64>(240, 255, tid, sc, sh, red, tab);

  // ---- transition: dump E -> Eg (row-major) + ETg (col-major), coalesced ----
  for (int idx = tid; idx < SL * SL; idx += NT) {
    int j = idx >> 8, i = idx & 255;
    if (i < j) ETg[idx] = sh[tab[j] + i];       // contiguous LDS read, coalesced store
  }
  for (int idx = tid; idx < SL * SL; idx += NT) {
    int i = idx >> 8, k = idx & 255;
    if (k > i) Eg[idx] = sh[tab[k] + i];        // one-time gather, coalesced store
  }
  float Hr = 0.f;
  if (tid == 0) {
    float Er = sh[tab[SL - 1]];                 // E[0,255] (before zeroing)
    Hr = (Er > 0.f) ? __expf(sc[SL - 1]) / Er : 0.f;
    g[SL - 1] = 1.0f;
  }
  __syncthreads();                              // drains vmcnt: E visible in L2

  // ---- re-init LDS triangle as H; write root ----
  for (int idx = tid * 4; idx < LDSF; idx += NT * 4)
    *(float4*)(sh + idx) = make_float4(0.f, 0.f, 0.f, 0.f);
  __syncthreads();
  if (tid == 0) sh[tab[SL - 1]] = Hr;           // H root at (0,255)
  __syncthreads();

  // ---- outside: H in LDS, E read-only global, raw lgkm barriers ----
  outsideB<64>(254, 240, tid, sc, g, Eg, ETg, sh, tab);
  outsideB<32>(239, 224, tid, sc, g, Eg, ETg, sh, tab);
  outsideB<16>(223, 192, tid, sc, g, Eg, ETg, sh, tab);
  outsideB<8>(191, 128, tid, sc, g, Eg, ETg, sh, tab);
  outsideB<4>(127, 1, tid, sc, g, Eg, ETg, sh, tab);
}

// ---------------- fallback: v2 global-memory kernel (proven, no transpose) ----
__device__ __forceinline__ float grpMaxR(float v, int G) {
#pragma unroll
  for (int o = 32; o; o >>= 1)
    if (o < G) v = fmaxf(v, __shfl_xor(v, o, 64));
  return v;
}
__device__ __forceinline__ float grpSumR(float v, int G) {
#pragma unroll
  for (int o = 32; o; o >>= 1)
    if (o < G) v += __shfl_xor(v, o, 64);
  return v;
}

__global__ __launch_bounds__(NT) void cyk_io_fb(
    const float* __restrict__ scores, float* __restrict__ out,
    float* __restrict__ ws) {
  const int b = blockIdx.x;
  const int tid = threadIdx.x;
  const size_t P = (size_t)SL * SL;
  const float* sc = scores + (size_t)b * P;
  float* g = out + (size_t)b * P;
  float* s = ws + (size_t)b * P;
  float* l = ws + (size_t)(BATCH + b) * P;

  for (int i = tid; i < SL - 1; i += NT) {
    s[i * SL + i + 1] = sc[i * SL + i + 1];
    l[i * SL + i + 1] = 0.f;
  }
  __syncthreads();

  for (int w = 2; w < SL; ++w) {
    const int cells = SL - w;
    int G = NT / cells;
    G = (G >= 64) ? 64 : (1 << (31 - __clz(G)));
    const int lg = 31 - __clz(G);
    const int c = tid >> lg;
    const int lig = tid & (G - 1);
    if (c < cells) {
      const int i = c, j = i + w;
      const float* srow = s + i * SL;
      float m = -INFINITY;
      for (int k = i + 1 + lig; k < j; k += G)
        m = fmaxf(m, srow[k] + s[k * SL + j]);
      m = grpMaxR(m, G);
      float sum = 0.f;
      for (int k = i + 1 + lig; k < j; k += G)
        sum += __expf(srow[k] + s[k * SL + j] - m);
      sum = grpSumR(sum, G);
      if (lig == 0) {
        const float lse = m + __logf(sum);
        s[i * SL + j] = sc[i * SL + j] + lse;
        l[i * SL + j] = lse;
      }
    }
    __syncthreads();
  }

  if (tid == 0) g[0 * SL + (SL - 1)] = 1.0f;
  __syncthreads();

  for (int w = SL - 2; w >= 1; --w) {
    const int cells = SL - w;
    int G = NT / cells;
    G = (G >= 64) ? 64 : (1 << (31 - __clz(G)));
    const int lg = 31 - __clz(G);
    const int c = tid >> lg;
    const int lig = tid & (G - 1);
    if (c < cells) {
      const int p = c, q = p + w;
      const float spq = s[p * SL + q];
      const int TR = SL - 1 - q;
      const int T = TR + p;
      float acc = 0.f;
      for (int t = lig; t < T; t += G) {
        if (t < TR) {
          const int j = q + 1 + t;
          acc += g[p * SL + j] * __expf(spq + s[q * SL + j] - l[p * SL + j]);
        } else {
          const int i = t - TR;
          acc += g[i * SL + q] * __expf(s[i * SL + p] + spq - l[i * SL + q]);
        }
      }
      acc = grpSumR(acc, G);
      if (lig == 0) g[p * SL + q] = acc;
    }
    __syncthreads();
  }
}

extern "C" void kernel_launch(void* const* d_in, const int* in_sizes, int n_in,
                              void* d_out, int out_size, void* d_ws, size_t ws_size,
                              hipStream_t stream) {
  const float* scores = (const float*)d_in[0];
  // d_in[1] = mask: triu(k=1) broadcast -> lens == SL-1 always; unused.
  float* out = (float*)d_out;
  float* ws = (float*)d_ws;

  const size_t sq = (size_t)SL * SL * sizeof(float);       // 256 KB
  hipMemsetAsync(d_out, 0, (size_t)BATCH * sq, stream);

  int dev = 0;
  hipGetDevice(&dev);
  int maxShm = 0;
  hipDeviceGetAttribute(&maxShm, hipDeviceAttributeMaxSharedMemoryPerBlock, dev);
  (void)hipFuncSetAttribute(reinterpret_cast<const void*>(cyk_exp),
                            hipFuncAttributeMaxDynamicSharedMemorySize, LDSB);

  if (maxShm >= LDSB && ws_size >= (size_t)2 * BATCH * sq) {
    hipMemsetAsync(ws, 0, (size_t)2 * BATCH * sq, stream);  // Eg/ETg guards = 0
    cyk_exp<<<BATCH, NT, LDSB, stream>>>(scores, out, ws);
  } else {
    cyk_io_fb<<<BATCH, NT, 0, stream>>>(scores, out, ws);
  }
}